// Round 3
// baseline (10811.012 us; speedup 1.0000x reference)
//
#include <hip/hip_runtime.h>
#include <math.h>

#define HIDDEN 300
#define ATOM_FDIM 136
#define BOND_IN 148
#define MAX_NB 6
#define N_MOLS 4096
#define APM 32
#define N_ATOMS (N_MOLS*APM)
#define N_BONDS (2*N_ATOMS)

#define BK 16

// Fallback scratch if ws_size is too small: 3 buffers of [N_BONDS][HIDDEN] f32.
// Uninitialized device global -> NOBITS section, allocated at module load.
__device__ float g_scratch[3ull * N_BONDS * HIDDEN];

// ---------------------------------------------------------------------------
// Fused GEMM: out = epilogue( A @ W )
//  MODE 0: A = fbonds [M][148]          -> out0 = A@W (binput), out1 = relu
//  MODE 1: A = gather-sum(msg, bgraph)  -> out0 = relu(binput + A@W)
//  MODE 2: A = concat(fatoms, gather-sum(msg, agraph)) -> out0 = relu(A@W + bias)
// Block: 512 threads (8 waves). BM=64 rows, BN=300 (full width), BK=16.
// Wave w owns rows [w*8, w*8+8); lane owns cols {lane, lane+64, ..., lane+256}.
// ---------------------------------------------------------------------------
template<int MODE>
__global__ __launch_bounds__(512)
void gemm_fused(const float* __restrict__ Adense,
                const float* __restrict__ msg,
                const int*   __restrict__ graph,
                const float* __restrict__ W,
                const float* __restrict__ binput,
                const float* __restrict__ bias,
                float* __restrict__ out0,
                float* __restrict__ out1,
                int K)
{
    __shared__ float As[BK][64];    // transposed A tile: As[kk][r]
    __shared__ float Bs[BK][300];

    const int tid  = threadIdx.x;
    const int wave = tid >> 6;
    const int lane = tid & 63;
    const int row0 = blockIdx.x * 64;
    const bool has4 = (lane < HIDDEN - 256);          // lane < 44
    const int  c4   = has4 ? (lane + 256) : 0;        // clamped (safe LDS read)

    float acc[8][5];
#pragma unroll
    for (int r = 0; r < 8; ++r)
#pragma unroll
        for (int c = 0; c < 5; ++c) acc[r][c] = 0.f;

    const int nk = (K + BK - 1) / BK;
    for (int kt = 0; kt < nk; ++kt) {
        const int k0 = kt * BK;
        // ---- stage W tile [BK][300]
        for (int i = tid; i < BK * 300; i += 512) {
            const int kk = i / 300;
            const int col = i - kk * 300;
            const int k = k0 + kk;
            Bs[kk][col] = (k < K) ? W[(size_t)k * HIDDEN + col] : 0.f;
        }
        // ---- stage A tile (16 consecutive threads = one row, contiguous k)
        for (int i = tid; i < BK * 64; i += 512) {
            const int r  = i >> 4;
            const int kk = i & (BK - 1);
            const int k  = k0 + kk;
            float v = 0.f;
            if (MODE == 0) {
                if (k < K) v = Adense[(size_t)(row0 + r) * BOND_IN + k];
            } else if (MODE == 1) {
                if (k < K) {
                    const int* g = graph + (size_t)(row0 + r) * MAX_NB;
#pragma unroll
                    for (int j = 0; j < MAX_NB; ++j)
                        v += msg[(size_t)g[j] * HIDDEN + k];
                }
            } else {
                if (k < ATOM_FDIM) {
                    v = Adense[(size_t)(row0 + r) * ATOM_FDIM + k];
                } else if (k < K) {
                    const int kc = k - ATOM_FDIM;
                    const int* g = graph + (size_t)(row0 + r) * MAX_NB;
#pragma unroll
                    for (int j = 0; j < MAX_NB; ++j)
                        v += msg[(size_t)g[j] * HIDDEN + kc];
                }
            }
            As[kk][r] = v;
        }
        __syncthreads();
        // ---- compute
#pragma unroll
        for (int kk = 0; kk < BK; ++kk) {
            float av[8], bv[5];
            *(float4*)&av[0] = *(const float4*)&As[kk][wave * 8];
            *(float4*)&av[4] = *(const float4*)&As[kk][wave * 8 + 4];
            bv[0] = Bs[kk][lane];
            bv[1] = Bs[kk][lane + 64];
            bv[2] = Bs[kk][lane + 128];
            bv[3] = Bs[kk][lane + 192];
            bv[4] = Bs[kk][c4];
#pragma unroll
            for (int r = 0; r < 8; ++r)
#pragma unroll
                for (int c = 0; c < 5; ++c)
                    acc[r][c] = fmaf(av[r], bv[c], acc[r][c]);
        }
        __syncthreads();
    }
    // ---- epilogue
    const int wrow = row0 + wave * 8;
#pragma unroll
    for (int r = 0; r < 8; ++r) {
        const size_t rowoff = (size_t)(wrow + r) * HIDDEN;
#pragma unroll
        for (int c = 0; c < 5; ++c) {
            const int col = lane + 64 * c;
            if (c < 4 || has4) {
                const size_t idx = rowoff + col;
                const float v = acc[r][c];
                if (MODE == 0)      { out0[idx] = v; out1[idx] = fmaxf(v, 0.f); }
                else if (MODE == 1) { out0[idx] = fmaxf(binput[idx] + v, 0.f); }
                else                { out0[idx] = fmaxf(v + bias[col], 0.f); }
            }
        }
    }
}

// ---------------------------------------------------------------------------
// Per-molecule self-attention pooling, fully fused. One block per molecule.
// h [32][300] in LDS; q/P share one LDS tile; softmax max-subtracted
// (logits reach ~1e6 in this problem -> mandatory).
// ---------------------------------------------------------------------------
#define HSS 305   // stride 305: (305*b)%32 = (17b)%32, gcd(17,32)=1 -> conflict-free col reads
#define ATTS 33

__global__ __launch_bounds__(512)
void attn_kernel(const float* __restrict__ atom_h,
                 const float* __restrict__ Wa,
                 const float* __restrict__ Wb,
                 const float* __restrict__ bb,
                 float* __restrict__ out)
{
    __shared__ float hs[APM][HSS];
    __shared__ float qs[APM][HSS];   // holds q, then P
    __shared__ float att[APM][ATTS];
    __shared__ float wsb[8][320];    // W staging; reused as reduction scratch

    const int tid  = threadIdx.x;
    const int wave = tid >> 6;
    const int lane = tid & 63;
    const int mol  = blockIdx.x;
    const bool has4 = (lane < 44);
    const int  c4   = has4 ? (lane + 256) : 0;
    const int  r0   = wave * 4;      // 8 waves x 4 rows = 32 atoms
    const float* hbase = atom_h + (size_t)mol * APM * HIDDEN;

    // zero K-padding cols 300..303 (read when K-tile overhangs 300)
    if (tid < 128) { const int a = tid >> 2, j = tid & 3; hs[a][300 + j] = 0.f; qs[a][300 + j] = 0.f; }
    for (int i = tid; i < APM * HIDDEN; i += 512) {
        const int a = i / HIDDEN;
        hs[a][i - a * HIDDEN] = hbase[i];
    }
    __syncthreads();

    // ---- q = h @ Wa
    float qacc[4][5];
#pragma unroll
    for (int r = 0; r < 4; ++r)
#pragma unroll
        for (int c = 0; c < 5; ++c) qacc[r][c] = 0.f;

    for (int k0 = 0; k0 < HIDDEN; k0 += 8) {
        for (int i = tid; i < 8 * HIDDEN; i += 512) {
            const int kk = i / HIDDEN;
            const int col = i - kk * HIDDEN;
            const int k = k0 + kk;
            wsb[kk][col] = (k < HIDDEN) ? Wa[(size_t)k * HIDDEN + col] : 0.f;
        }
        __syncthreads();
#pragma unroll
        for (int kk = 0; kk < 8; ++kk) {
            float bv[5];
            bv[0] = wsb[kk][lane];        bv[1] = wsb[kk][lane + 64];
            bv[2] = wsb[kk][lane + 128];  bv[3] = wsb[kk][lane + 192];
            bv[4] = wsb[kk][c4];
#pragma unroll
            for (int r = 0; r < 4; ++r) {
                const float a = hs[r0 + r][k0 + kk];   // zero-padded past 300
#pragma unroll
                for (int c = 0; c < 5; ++c) qacc[r][c] = fmaf(a, bv[c], qacc[r][c]);
            }
        }
        __syncthreads();
    }
#pragma unroll
    for (int r = 0; r < 4; ++r)
#pragma unroll
        for (int c = 0; c < 5; ++c) {
            const int col = lane + 64 * c;
            if (c < 4 || has4) qs[r0 + r][col] = qacc[r][c];
        }
    __syncthreads();

    // ---- logits = q @ h^T
    for (int e = tid; e < APM * APM; e += 512) {
        const int a = e >> 5, b = e & 31;
        float s = 0.f;
#pragma unroll 4
        for (int k = 0; k < HIDDEN; ++k) s = fmaf(qs[a][k], hs[b][k], s);
        att[a][b] = s;
    }
    __syncthreads();

    // ---- softmax rows (max-subtracted)
    if (tid < APM) {
        float m = -3.4e38f;
        for (int b = 0; b < APM; ++b) m = fmaxf(m, att[tid][b]);
        float s = 0.f;
        for (int b = 0; b < APM; ++b) { const float e = expf(att[tid][b] - m); att[tid][b] = e; s += e; }
        const float inv = 1.f / s;
        for (int b = 0; b < APM; ++b) att[tid][b] *= inv;
    }
    __syncthreads();

    // ---- P = att @ h   (K=32)
    float pacc[4][5];
#pragma unroll
    for (int r = 0; r < 4; ++r)
#pragma unroll
        for (int c = 0; c < 5; ++c) pacc[r][c] = 0.f;
#pragma unroll 4
    for (int b = 0; b < APM; ++b) {
        float hb[5];
        hb[0] = hs[b][lane];        hb[1] = hs[b][lane + 64];
        hb[2] = hs[b][lane + 128];  hb[3] = hs[b][lane + 192];
        hb[4] = hs[b][c4];
#pragma unroll
        for (int r = 0; r < 4; ++r) {
            const float a = att[r0 + r][b];
#pragma unroll
            for (int c = 0; c < 5; ++c) pacc[r][c] = fmaf(a, hb[c], pacc[r][c]);
        }
    }
#pragma unroll
    for (int r = 0; r < 4; ++r)
#pragma unroll
        for (int c = 0; c < 5; ++c) {
            const int col = lane + 64 * c;
            if (c < 4 || has4) qs[r0 + r][col] = pacc[r][c];   // P overwrites q
        }
    __syncthreads();

    // ---- att_h = relu(P @ Wb + bb)
    float aacc[4][5];
#pragma unroll
    for (int r = 0; r < 4; ++r)
#pragma unroll
        for (int c = 0; c < 5; ++c) aacc[r][c] = 0.f;

    for (int k0 = 0; k0 < HIDDEN; k0 += 8) {
        for (int i = tid; i < 8 * HIDDEN; i += 512) {
            const int kk = i / HIDDEN;
            const int col = i - kk * HIDDEN;
            const int k = k0 + kk;
            wsb[kk][col] = (k < HIDDEN) ? Wb[(size_t)k * HIDDEN + col] : 0.f;
        }
        __syncthreads();
#pragma unroll
        for (int kk = 0; kk < 8; ++kk) {
            float bv[5];
            bv[0] = wsb[kk][lane];        bv[1] = wsb[kk][lane + 64];
            bv[2] = wsb[kk][lane + 128];  bv[3] = wsb[kk][lane + 192];
            bv[4] = wsb[kk][c4];
#pragma unroll
            for (int r = 0; r < 4; ++r) {
                const float a = qs[r0 + r][k0 + kk];
#pragma unroll
                for (int c = 0; c < 5; ++c) aacc[r][c] = fmaf(a, bv[c], aacc[r][c]);
            }
        }
        __syncthreads();
    }

    // ---- per-wave partial of sum_a (h + relu(att_h)) ; reduce across waves
    float bbv[5];
    bbv[0] = bb[lane];        bbv[1] = bb[lane + 64];
    bbv[2] = bb[lane + 128];  bbv[3] = bb[lane + 192];
    bbv[4] = bb[c4];
    float part[5];
#pragma unroll
    for (int c = 0; c < 5; ++c) part[c] = 0.f;
#pragma unroll
    for (int r = 0; r < 4; ++r) {
#pragma unroll
        for (int c = 0; c < 5; ++c) {
            const int col = (c < 4) ? (lane + 64 * c) : c4;
            part[c] += hs[r0 + r][col] + fmaxf(aacc[r][c] + bbv[c], 0.f);
        }
    }
    __syncthreads();   // wsb free -> reuse as red[8][320]
#pragma unroll
    for (int c = 0; c < 5; ++c) {
        const int col = lane + 64 * c;
        if (c < 4 || has4) wsb[wave][col] = part[c];
    }
    __syncthreads();
    for (int col = tid; col < HIDDEN; col += 512) {
        float s = 0.f;
#pragma unroll
        for (int w = 0; w < 8; ++w) s += wsb[w][col];
        out[(size_t)mol * HIDDEN + col] = s * (1.0f / APM);
    }
}

// ---------------------------------------------------------------------------
extern "C" void kernel_launch(void* const* d_in, const int* in_sizes, int n_in,
                              void* d_out, int out_size, void* d_ws, size_t ws_size,
                              hipStream_t stream)
{
    const float* fatoms = (const float*)d_in[0];
    const float* fbonds = (const float*)d_in[1];
    const int*   agraph = (const int*)d_in[2];
    const int*   bgraph = (const int*)d_in[3];
    const float* W_i    = (const float*)d_in[4];
    const float* W_h    = (const float*)d_in[5];
    const float* W_o    = (const float*)d_in[6];
    const float* b_o    = (const float*)d_in[7];
    const float* W_a    = (const float*)d_in[8];
    const float* W_b    = (const float*)d_in[9];
    const float* b_b    = (const float*)d_in[10];
    float* out = (float*)d_out;

    // scratch: binput | msg0 | msg1  (3 x 314.6 MB). Use d_ws when it is big
    // enough; otherwise fall back to the device-global buffer (capture-safe:
    // hipGetSymbolAddress is a query, not a stream op). Same path every call.
    const size_t need = 3ull * N_BONDS * HIDDEN * sizeof(float);
    float* base;
    if (ws_size >= need) {
        base = (float*)d_ws;
    } else {
        void* p = nullptr;
        (void)hipGetSymbolAddress(&p, HIP_SYMBOL(g_scratch));
        base = (float*)p;
    }
    float* binput = base;
    float* msg0   = binput + (size_t)N_BONDS * HIDDEN;
    float* msg1   = msg0   + (size_t)N_BONDS * HIDDEN;
    float* atom_h = binput;   // reuse after last message iteration

    const dim3 blk(512);

    // binput = fbonds @ W_i ; msg0 = relu(binput)
    gemm_fused<0><<<N_BONDS / 64, blk, 0, stream>>>(
        fbonds, nullptr, nullptr, W_i, nullptr, nullptr, binput, msg0, BOND_IN);

    // 5 message-passing iterations (DEPTH-1)
    const float* cur = msg0;
    float* nxt = msg1;
    for (int it = 0; it < 5; ++it) {
        gemm_fused<1><<<N_BONDS / 64, blk, 0, stream>>>(
            nullptr, cur, bgraph, W_h, binput, nullptr, nxt, nullptr, HIDDEN);
        float* t = nxt; nxt = (float*)cur; cur = t;
    }
    // final message is in `cur`

    // atom_h = relu(concat(fatoms, gather(msg)) @ W_o + b_o)  (reuses binput)
    gemm_fused<2><<<N_ATOMS / 64, blk, 0, stream>>>(
        fatoms, cur, agraph, W_o, nullptr, b_o, atom_h, nullptr, ATOM_FDIM + HIDDEN);

    // fused per-molecule attention pooling -> d_out
    attn_kernel<<<N_MOLS, blk, 0, stream>>>(atom_h, W_a, W_b, b_b, out);
}